// Round 5
// baseline (910.512 us; speedup 1.0000x reference)
//
#include <hip/hip_runtime.h>
#include <math.h>

#define NROWS 16384
#define GATES 5
#define HDIM 512

using bf16x8 = __attribute__((ext_vector_type(8))) short;
using f32x4  = __attribute__((ext_vector_type(4))) float;

__device__ inline float b2f(unsigned short s) {
  unsigned int u = ((unsigned int)s) << 16;
  return __builtin_bit_cast(float, u);
}
__device__ inline unsigned short f2b(float f) {
  unsigned int u = __builtin_bit_cast(unsigned int, f);
  u += 0x7fffu + ((u >> 16) & 1u);   // RNE
  return (unsigned short)(u >> 16);
}

// fast activations: v_exp_f32 (2^x) + v_rcp_f32, ~5 inst, saturate correctly
__device__ inline float fast_sigmoid(float x) {
  float t = __builtin_amdgcn_exp2f(-1.4426950408889634f * x);
  return __builtin_amdgcn_rcpf(1.0f + t);
}
__device__ inline float fast_tanh(float x) {
  float t = __builtin_amdgcn_exp2f(2.8853900817779268f * x);
  return 1.0f - 2.0f * __builtin_amdgcn_rcpf(1.0f + t);
}

// ---------------- packing / conversion kernels (f32 -> bf16) ----------------

__global__ void pack_x(const float* __restrict__ word,
                       const float* __restrict__ tag,
                       const float* __restrict__ rel,
                       unsigned short* __restrict__ xcat) {
  int idx = blockIdx.x * 256 + threadIdx.x;       // N*512
  int n = idx >> 9, c = idx & 511;
  float v = 0.f;
  if (c < 300)      v = word[n * 300 + c];
  else if (c < 350) v = tag[n * 50 + (c - 300)];
  else if (c < 400) v = rel[n * 50 + (c - 350)];
  xcat[idx] = f2b(v);
}

__global__ void pack_w(const float* __restrict__ Ww,
                       const float* __restrict__ Wt,
                       const float* __restrict__ Wr,
                       unsigned short* __restrict__ Wcat) {
  int idx = blockIdx.x * 256 + threadIdx.x;       // G*512*512
  int gh = idx >> 9;                              // g*512 + h
  int c = idx & 511;
  float v = 0.f;
  if (c < 300)      v = Ww[gh * 300 + c];
  else if (c < 350) v = Wt[gh * 50 + (c - 300)];
  else if (c < 400) v = Wr[gh * 50 + (c - 350)];
  Wcat[idx] = f2b(v);
}

__global__ void cvt_bf16(const float* __restrict__ in,
                         unsigned short* __restrict__ out, int n) {
  int i = (blockIdx.x * 256 + threadIdx.x) * 4;
  if (i >= n) return;
  float4 v = *(const float4*)(in + i);
  ushort4 o;
  o.x = f2b(v.x); o.y = f2b(v.y); o.z = f2b(v.z); o.w = f2b(v.w);
  *(ushort4*)(out + i) = o;
}

__global__ void pack_bias(const float* __restrict__ bw, const float* __restrict__ bt,
                          const float* __restrict__ br, const float* __restrict__ bh,
                          const float* __restrict__ bl, const float* __restrict__ bhp,
                          const float* __restrict__ bk,
                          float* bias0, float* bias1, float* bias2, float* biasD) {
  int i = blockIdx.x * 256 + threadIdx.x;         // G*512
  if (i < GATES * HDIM) {
    bias0[i] = bw[i] + bt[i] + br[i];
    bias1[i] = bh[i];
    bias2[i] = bl[i];
    biasD[i] = bhp[i] + bk[i];
  }
}

// ---------------- GEMM: LDS-free, barrier-free, register-direct fragments ----
// NT layout + mfma_16x16x32: A-frag = A[row][k..k+8), B-frag = W[col][k..k+8)
// — both 16 contiguous bytes in global. Load straight to VGPR, no staging.
// grid: x = col_tile*GATES + gate (20), y = row_tile (128); 128x128/block, 4 waves.
// MODE 0: Out = tanh(A[g?]*W[g]^T + bias[g])
// MODE 1: Out = act_g(A1*W1[g]^T + A2*W2[g]^T + bias[g] + Madd[g])

template<int MODE>
__global__ __launch_bounds__(256, 2) void gemm_reg(
    const unsigned short* __restrict__ A1, const unsigned short* __restrict__ A2,
    const unsigned short* __restrict__ W1, const unsigned short* __restrict__ W2,
    const float* __restrict__ bias,
    const unsigned short* __restrict__ Madd,
    unsigned short* __restrict__ Out,
    int aPerGate)
{
  const int t = threadIdx.x;
  const int g    = blockIdx.x % GATES;
  const int col0 = (blockIdx.x / GATES) * 128;   // H tile
  const int row0 = blockIdx.y * 128;             // N tile

  const size_t wslab = (size_t)g * HDIM * HDIM;
  const size_t aslab = aPerGate ? (size_t)g * NROWS * HDIM : 0;

  const int w = t >> 6, l = t & 63;
  const int fr = l & 15;
  const int kb8 = (l >> 4) * 8;                  // k sub-offset 0/8/16/24
  const int arow = row0 + (w >> 1) * 64 + fr;    // + mi*16
  const int bcol = col0 + (w & 1) * 64 + fr;     // + ni*16

  f32x4 acc[4][4];
#pragma unroll
  for (int mi = 0; mi < 4; ++mi)
#pragma unroll
    for (int ni = 0; ni < 4; ++ni)
      acc[mi][ni] = (f32x4){0.f, 0.f, 0.f, 0.f};

  // per-fragment-row base pointers (K-walk folds into the 13-bit load imm)
  const unsigned short* ab[4];
  const unsigned short* bb[4];

  auto kloop = [&](const unsigned short* Abase, const unsigned short* Wbase) {
#pragma unroll
    for (int mi = 0; mi < 4; ++mi) ab[mi] = Abase + (size_t)(arow + mi * 16) * HDIM + kb8;
#pragma unroll
    for (int ni = 0; ni < 4; ++ni) bb[ni] = Wbase + (size_t)(bcol + ni * 16) * HDIM + kb8;
#pragma unroll
    for (int s = 0; s < 16; ++s) {               // K = 512, 32 per step
      bf16x8 af[4], bf[4];
#pragma unroll
      for (int mi = 0; mi < 4; ++mi)
        af[mi] = *reinterpret_cast<const bf16x8*>(ab[mi] + s * 32);
#pragma unroll
      for (int ni = 0; ni < 4; ++ni)
        bf[ni] = *reinterpret_cast<const bf16x8*>(bb[ni] + s * 32);
#pragma unroll
      for (int mi = 0; mi < 4; ++mi)
#pragma unroll
        for (int ni = 0; ni < 4; ++ni)
          acc[mi][ni] = __builtin_amdgcn_mfma_f32_16x16x32_bf16(af[mi], bf[ni], acc[mi][ni], 0, 0, 0);
    }
  };

  kloop(A1 + aslab, W1 + wslab);
  if (MODE == 1) kloop(A2, W2 + wslab);

  // epilogue: C/D layout col=lane&15, row=(lane>>4)*4+j   [m89/m91]
  const int crow = (l >> 4) * 4, ccol = l & 15;
  const int wrow = (w >> 1) * 64, wcol = (w & 1) * 64;
  unsigned short* outg = Out + (size_t)g * NROWS * HDIM;
#pragma unroll
  for (int mi = 0; mi < 4; ++mi) {
#pragma unroll
    for (int ni = 0; ni < 4; ++ni) {
      const int hcol = col0 + wcol + ni * 16 + ccol;
      const float bb2 = bias[g * HDIM + hcol];
#pragma unroll
      for (int j = 0; j < 4; ++j) {
        const int nrow = row0 + wrow + mi * 16 + crow + j;
        float v = acc[mi][ni][j] + bb2;
        if (MODE == 1) {
          v += b2f(Madd[(size_t)g * NROWS * HDIM + (size_t)nrow * HDIM + hcol]);
          v = (g < 4) ? fast_sigmoid(v) : fast_tanh(v);
        } else {
          v = fast_tanh(v);
        }
        outg[(size_t)nrow * HDIM + hcol] = f2b(v);
      }
    }
  }
}

// ---------------- final elementwise combine (f32 q/c_prev, f32 out) ----------------

__device__ inline float exb(const uint4& v, int j) {
  unsigned int wd = ((const unsigned int*)&v)[j >> 1];
  return b2f((unsigned short)(wd >> ((j & 1) * 16)));
}

__global__ void combine(const unsigned short* __restrict__ gates,
                        const float* __restrict__ q,
                        const float* __restrict__ cp,
                        float* __restrict__ out) {
  const size_t NM = (size_t)NROWS * HDIM;
  size_t i8 = ((size_t)blockIdx.x * 256 + threadIdx.x) * 8;
  if (i8 >= NM) return;
  uint4 gi = *(const uint4*)(gates + 0 * NM + i8);
  uint4 gf = *(const uint4*)(gates + 1 * NM + i8);
  uint4 gl = *(const uint4*)(gates + 2 * NM + i8);
  uint4 go = *(const uint4*)(gates + 3 * NM + i8);
  uint4 gu = *(const uint4*)(gates + 4 * NM + i8);
  float4 q0 = *(const float4*)(q + i8);
  float4 q1 = *(const float4*)(q + i8 + 4);
  float4 p0 = *(const float4*)(cp + i8);
  float4 p1 = *(const float4*)(cp + i8 + 4);
  float qv[8] = {q0.x, q0.y, q0.z, q0.w, q1.x, q1.y, q1.z, q1.w};
  float pv[8] = {p0.x, p0.y, p0.z, p0.w, p1.x, p1.y, p1.z, p1.w};
  float hv[8], cv[8];
#pragma unroll
  for (int j = 0; j < 8; ++j) {
    float c = exb(gi, j) * exb(gu, j) + exb(gf, j) * qv[j] + exb(gl, j) * pv[j];
    hv[j] = exb(go, j) * fast_tanh(c);
    cv[j] = c;
  }
  *(float4*)(out + i8)      = make_float4(hv[0], hv[1], hv[2], hv[3]);
  *(float4*)(out + i8 + 4)  = make_float4(hv[4], hv[5], hv[6], hv[7]);
  *(float4*)(out + NM + i8)     = make_float4(cv[0], cv[1], cv[2], cv[3]);
  *(float4*)(out + NM + i8 + 4) = make_float4(cv[4], cv[5], cv[6], cv[7]);
}

// ---------------- launch ----------------

extern "C" void kernel_launch(void* const* d_in, const int* in_sizes, int n_in,
                              void* d_out, int out_size, void* d_ws, size_t ws_size,
                              hipStream_t stream) {
  const float* word  = (const float*)d_in[0];
  const float* tag   = (const float*)d_in[1];
  const float* rel   = (const float*)d_in[2];
  const float* kin   = (const float*)d_in[3];
  const float* qin   = (const float*)d_in[4];
  const float* hprev = (const float*)d_in[5];
  const float* cprev = (const float*)d_in[6];
  const float* Ww    = (const float*)d_in[7];
  const float* bw    = (const float*)d_in[8];
  const float* Wt    = (const float*)d_in[9];
  const float* bt    = (const float*)d_in[10];
  const float* Wr    = (const float*)d_in[11];
  const float* br    = (const float*)d_in[12];
  const float* Wh    = (const float*)d_in[13];
  const float* bh    = (const float*)d_in[14];
  const float* Wl    = (const float*)d_in[15];
  const float* bl    = (const float*)d_in[16];
  const float* Whp   = (const float*)d_in[17];
  const float* bhp   = (const float*)d_in[18];
  const float* Wk    = (const float*)d_in[19];
  const float* bk    = (const float*)d_in[20];

  char* ws = (char*)d_ws;
  unsigned short* xcat   = (unsigned short*)(ws);                 // 16,777,216 B
  unsigned short* Wcat   = (unsigned short*)(ws + 16777216);      //  2,621,440 B
  unsigned short* Whb    = (unsigned short*)(ws + 19398656);      //  2,621,440 B
  unsigned short* Wlb    = (unsigned short*)(ws + 22020096);      //  2,621,440 B
  unsigned short* Whpb   = (unsigned short*)(ws + 24641536);      //  2,621,440 B
  unsigned short* Wkb    = (unsigned short*)(ws + 27262976);      //  2,621,440 B
  unsigned short* hprevb = (unsigned short*)(ws + 29884416);      // 16,777,216 B
  unsigned short* kb16   = (unsigned short*)(ws + 46661632);      // 16,777,216 B
  float* bias0           = (float*)(ws + 63438848);               //     10,240 B
  float* bias1           = (float*)(ws + 63449088);
  float* bias2           = (float*)(ws + 63459328);
  float* biasD           = (float*)(ws + 63469568);
  unsigned short* bufA   = (unsigned short*)(ws + 63479808);      // 83,886,080 B
  unsigned short* bufB   = (unsigned short*)(ws + 147365888);     // 83,886,080 B
  // total: 231,251,968 B

  pack_x<<<32768, 256, 0, stream>>>(word, tag, rel, xcat);
  pack_w<<<5120, 256, 0, stream>>>(Ww, Wt, Wr, Wcat);
  cvt_bf16<<<1280, 256, 0, stream>>>(Wh, Whb, 1310720);
  cvt_bf16<<<1280, 256, 0, stream>>>(Wl, Wlb, 1310720);
  cvt_bf16<<<1280, 256, 0, stream>>>(Whp, Whpb, 1310720);
  cvt_bf16<<<1280, 256, 0, stream>>>(Wk, Wkb, 1310720);
  cvt_bf16<<<8192, 256, 0, stream>>>(hprev, hprevb, 8388608);
  cvt_bf16<<<8192, 256, 0, stream>>>(kin, kb16, 8388608);
  pack_bias<<<10, 256, 0, stream>>>(bw, bt, br, bh, bl, bhp, bk, bias0, bias1, bias2, biasD);

  dim3 grid((HDIM / 128) * GATES, NROWS / 128);
  // h0 = tanh(xcat W0^T + b0)
  gemm_reg<0><<<grid, 256, 0, stream>>>(xcat, nullptr, Wcat, nullptr, bias0, nullptr, bufA, 0);
  // h1 = tanh(h0 Whid^T + bhid)
  gemm_reg<0><<<grid, 256, 0, stream>>>(bufA, nullptr, Whb, nullptr, bias1, nullptr, bufB, 1);
  // m = tanh(h1 Wlast^T + blast)
  gemm_reg<0><<<grid, 256, 0, stream>>>(bufB, nullptr, Wlb, nullptr, bias2, nullptr, bufA, 1);
  // gates = act(hprev Whp^T + k Wk^T + bhp + bk + m)
  gemm_reg<1><<<grid, 256, 0, stream>>>(hprevb, kb16, Whpb, Wkb, biasD, bufA, bufB, 0);
  // c = i*u + f_down*q + f_left*c_prev ; h = o*tanh(c)
  combine<<<4096, 256, 0, stream>>>(bufB, qin, cprev, (float*)d_out);
}

// Round 6
// 550.672 us; speedup vs baseline: 1.6535x; 1.6535x over previous
//
#include <hip/hip_runtime.h>
#include <math.h>

#define NROWS 16384
#define GATES 5
#define HDIM 512

using bf16x8 = __attribute__((ext_vector_type(8))) short;
using f32x4  = __attribute__((ext_vector_type(4))) float;

__device__ inline float b2f(unsigned short s) {
  unsigned int u = ((unsigned int)s) << 16;
  return __builtin_bit_cast(float, u);
}
__device__ inline unsigned short f2b(float f) {
  unsigned int u = __builtin_bit_cast(unsigned int, f);
  u += 0x7fffu + ((u >> 16) & 1u);   // RNE
  return (unsigned short)(u >> 16);
}

// fast activations: v_exp_f32 (2^x) + v_rcp_f32, ~5 inst, saturate correctly
__device__ inline float fast_sigmoid(float x) {
  float t = __builtin_amdgcn_exp2f(-1.4426950408889634f * x);
  return __builtin_amdgcn_rcpf(1.0f + t);
}
__device__ inline float fast_tanh(float x) {
  float t = __builtin_amdgcn_exp2f(2.8853900817779268f * x);
  return 1.0f - 2.0f * __builtin_amdgcn_rcpf(1.0f + t);
}

__device__ inline void gload_lds16(const unsigned short* g, unsigned short* l) {
  __builtin_amdgcn_global_load_lds(
      (const __attribute__((address_space(1))) unsigned int*)(g),
      (__attribute__((address_space(3))) unsigned int*)(l), 16, 0, 0);
}

// ---------------- packing / conversion kernels (f32 -> bf16) ----------------

__global__ void pack_x(const float* __restrict__ word,
                       const float* __restrict__ tag,
                       const float* __restrict__ rel,
                       unsigned short* __restrict__ xcat) {
  int idx = blockIdx.x * 256 + threadIdx.x;       // N*512
  int n = idx >> 9, c = idx & 511;
  float v = 0.f;
  if (c < 300)      v = word[n * 300 + c];
  else if (c < 350) v = tag[n * 50 + (c - 300)];
  else if (c < 400) v = rel[n * 50 + (c - 350)];
  xcat[idx] = f2b(v);
}

__global__ void pack_w(const float* __restrict__ Ww,
                       const float* __restrict__ Wt,
                       const float* __restrict__ Wr,
                       unsigned short* __restrict__ Wcat) {
  int idx = blockIdx.x * 256 + threadIdx.x;       // G*512*512
  int gh = idx >> 9;                              // g*512 + h
  int c = idx & 511;
  float v = 0.f;
  if (c < 300)      v = Ww[gh * 300 + c];
  else if (c < 350) v = Wt[gh * 50 + (c - 300)];
  else if (c < 400) v = Wr[gh * 50 + (c - 350)];
  Wcat[idx] = f2b(v);
}

__global__ void cvt_bf16(const float* __restrict__ in,
                         unsigned short* __restrict__ out, int n) {
  int i = (blockIdx.x * 256 + threadIdx.x) * 4;
  if (i >= n) return;
  float4 v = *(const float4*)(in + i);
  ushort4 o;
  o.x = f2b(v.x); o.y = f2b(v.y); o.z = f2b(v.z); o.w = f2b(v.w);
  *(ushort4*)(out + i) = o;
}

__global__ void pack_bias(const float* __restrict__ bw, const float* __restrict__ bt,
                          const float* __restrict__ br, const float* __restrict__ bh,
                          const float* __restrict__ bl, const float* __restrict__ bhp,
                          const float* __restrict__ bk,
                          float* bias0, float* bias1, float* bias2, float* biasD) {
  int i = blockIdx.x * 256 + threadIdx.x;         // G*512
  if (i < GATES * HDIM) {
    bias0[i] = bw[i] + bt[i] + br[i];
    bias1[i] = bh[i];
    bias2[i] = bl[i];
    biasD[i] = bhp[i] + bk[i];
  }
}

// ---------------- GEMM: 128x128 tile, BK=32, 4 waves, 4-deep counted-vmcnt ----
// pipeline: stage chunks s..s+2 in flight; per iter: vmcnt(8)+s_barrier (never
// drain to 0 mid-loop), stage(s+3), MFMA on chunk s.  T2 swizzle: LDS dest is
// linear (gload_lds constraint m104), global SOURCE pre-swizzled slot^= (row&3),
// ds_read applies the same XOR -> conflict-free b128 reads.
// MODE 0: Out = tanh(A*W[g]^T + bias[g]) ; MODE 1: + A2*W2[g]^T + Madd, gate act.

template<int MODE>
__global__ __launch_bounds__(256, 2) void gemm_nt(
    const unsigned short* __restrict__ A1, const unsigned short* __restrict__ A2,
    const unsigned short* __restrict__ W1, const unsigned short* __restrict__ W2,
    const float* __restrict__ bias,
    const unsigned short* __restrict__ Madd,
    unsigned short* __restrict__ Out,
    int aPerGate, int S)       // S = K/32 chunks (16 or 32)
{
  __shared__ __align__(16) unsigned short Alds[4][128 * 32];
  __shared__ __align__(16) unsigned short Blds[4][128 * 32];

  const int t = threadIdx.x;
  const int row0 = blockIdx.x * 128;   // N tile
  const int col0 = blockIdx.y * 128;   // H tile
  const int g = blockIdx.z;

  const size_t wslab = (size_t)g * HDIM * HDIM;
  const size_t aslab = aPerGate ? (size_t)g * NROWS * HDIM : 0;

  f32x4 acc[4][4];
#pragma unroll
  for (int mi = 0; mi < 4; ++mi)
#pragma unroll
    for (int ni = 0; ni < 4; ++ni)
      acc[mi][ni] = (f32x4){0.f, 0.f, 0.f, 0.f};

  const int w = t >> 6, l = t & 63;
  const int wrow = (w >> 1) * 64, wcol = (w & 1) * 64;
  const int fr = l & 15;
  const int effs = ((l >> 4) ^ (l & 3)) * 8;   // swizzled k-slot (elements)

  // staging map: issue j covers LDS bytes [j*4096 + t*16) — lane-linear (m104).
  const int srb = t >> 2;        // row base 0..63 (+ j*64)
  const int ssl = t & 3;         // 16B slot
  auto stage = [&](int c, int buf) {
    const unsigned short* Ab; const unsigned short* Wb; int kloc;
    if (MODE == 1 && c >= 16) { Ab = A2;         Wb = W2 + wslab; kloc = (c - 16) * 32; }
    else                      { Ab = A1 + aslab; Wb = W1 + wslab; kloc = c * 32; }
#pragma unroll
    for (int j = 0; j < 2; ++j) {
      const int r  = j * 64 + srb;
      const int sg = (ssl ^ (r & 3)) * 8;        // inverse-swizzled source slot
      gload_lds16(Ab + (size_t)(row0 + r) * HDIM + kloc + sg, &Alds[buf][j * 2048 + t * 8]);
      gload_lds16(Wb + (size_t)(col0 + r) * HDIM + kloc + sg, &Blds[buf][j * 2048 + t * 8]);
    }
  };

  stage(0, 0); stage(1, 1); stage(2, 2);   // 12 loads/thread in flight

  for (int s = 0; s < S; ++s) {
    // wait for chunk s only (4 loads); keep later chunks in flight
    if (s <= S - 3)      asm volatile("s_waitcnt vmcnt(8)" ::: "memory");
    else if (s == S - 2) asm volatile("s_waitcnt vmcnt(4)" ::: "memory");
    else                 asm volatile("s_waitcnt vmcnt(0)" ::: "memory");
    __builtin_amdgcn_s_barrier();

    if (s + 3 < S) stage(s + 3, (s + 3) & 3);

    const int buf = s & 3;
    bf16x8 af[4], bfv[4];
#pragma unroll
    for (int mi = 0; mi < 4; ++mi)
      af[mi] = *reinterpret_cast<const bf16x8*>(&Alds[buf][(wrow + mi * 16 + fr) * 32 + effs]);
#pragma unroll
    for (int ni = 0; ni < 4; ++ni)
      bfv[ni] = *reinterpret_cast<const bf16x8*>(&Blds[buf][(wcol + ni * 16 + fr) * 32 + effs]);
    __builtin_amdgcn_s_setprio(1);
#pragma unroll
    for (int mi = 0; mi < 4; ++mi)
#pragma unroll
      for (int ni = 0; ni < 4; ++ni)
        acc[mi][ni] = __builtin_amdgcn_mfma_f32_16x16x32_bf16(af[mi], bfv[ni], acc[mi][ni], 0, 0, 0);
    __builtin_amdgcn_s_setprio(0);
  }

  // epilogue: C/D layout col=lane&15, row=(lane>>4)*4+j   [m89/m91]
  const int crow = (l >> 4) * 4, ccol = l & 15;
  unsigned short* outg = Out + (size_t)g * NROWS * HDIM;
#pragma unroll
  for (int mi = 0; mi < 4; ++mi) {
#pragma unroll
    for (int ni = 0; ni < 4; ++ni) {
      const int hcol = col0 + wcol + ni * 16 + ccol;
      const float bb = bias[g * HDIM + hcol];
#pragma unroll
      for (int j = 0; j < 4; ++j) {
        const int nrow = row0 + wrow + mi * 16 + crow + j;
        float v = acc[mi][ni][j] + bb;
        if (MODE == 1) {
          v += b2f(Madd[(size_t)g * NROWS * HDIM + (size_t)nrow * HDIM + hcol]);
          v = (g < 4) ? fast_sigmoid(v) : fast_tanh(v);
        } else {
          v = fast_tanh(v);
        }
        outg[(size_t)nrow * HDIM + hcol] = f2b(v);
      }
    }
  }
}

// ---------------- final elementwise combine (f32 q/c_prev, f32 out) ----------------

__device__ inline float exb(const uint4& v, int j) {
  unsigned int wd = ((const unsigned int*)&v)[j >> 1];
  return b2f((unsigned short)(wd >> ((j & 1) * 16)));
}

__global__ void combine(const unsigned short* __restrict__ gates,
                        const float* __restrict__ q,
                        const float* __restrict__ cp,
                        float* __restrict__ out) {
  const size_t NM = (size_t)NROWS * HDIM;
  size_t i8 = ((size_t)blockIdx.x * 256 + threadIdx.x) * 8;
  if (i8 >= NM) return;
  uint4 gi = *(const uint4*)(gates + 0 * NM + i8);
  uint4 gf = *(const uint4*)(gates + 1 * NM + i8);
  uint4 gl = *(const uint4*)(gates + 2 * NM + i8);
  uint4 go = *(const uint4*)(gates + 3 * NM + i8);
  uint4 gu = *(const uint4*)(gates + 4 * NM + i8);
  float4 q0 = *(const float4*)(q + i8);
  float4 q1 = *(const float4*)(q + i8 + 4);
  float4 p0 = *(const float4*)(cp + i8);
  float4 p1 = *(const float4*)(cp + i8 + 4);
  float qv[8] = {q0.x, q0.y, q0.z, q0.w, q1.x, q1.y, q1.z, q1.w};
  float pv[8] = {p0.x, p0.y, p0.z, p0.w, p1.x, p1.y, p1.z, p1.w};
  float hv[8], cv[8];
#pragma unroll
  for (int j = 0; j < 8; ++j) {
    float c = exb(gi, j) * exb(gu, j) + exb(gf, j) * qv[j] + exb(gl, j) * pv[j];
    hv[j] = exb(go, j) * fast_tanh(c);
    cv[j] = c;
  }
  *(float4*)(out + i8)      = make_float4(hv[0], hv[1], hv[2], hv[3]);
  *(float4*)(out + i8 + 4)  = make_float4(hv[4], hv[5], hv[6], hv[7]);
  *(float4*)(out + NM + i8)     = make_float4(cv[0], cv[1], cv[2], cv[3]);
  *(float4*)(out + NM + i8 + 4) = make_float4(cv[4], cv[5], cv[6], cv[7]);
}

// ---------------- launch ----------------

extern "C" void kernel_launch(void* const* d_in, const int* in_sizes, int n_in,
                              void* d_out, int out_size, void* d_ws, size_t ws_size,
                              hipStream_t stream) {
  const float* word  = (const float*)d_in[0];
  const float* tag   = (const float*)d_in[1];
  const float* rel   = (const float*)d_in[2];
  const float* kin   = (const float*)d_in[3];
  const float* qin   = (const float*)d_in[4];
  const float* hprev = (const float*)d_in[5];
  const float* cprev = (const float*)d_in[6];
  const float* Ww    = (const float*)d_in[7];
  const float* bw    = (const float*)d_in[8];
  const float* Wt    = (const float*)d_in[9];
  const float* bt    = (const float*)d_in[10];
  const float* Wr    = (const float*)d_in[11];
  const float* br    = (const float*)d_in[12];
  const float* Wh    = (const float*)d_in[13];
  const float* bh    = (const float*)d_in[14];
  const float* Wl    = (const float*)d_in[15];
  const float* bl    = (const float*)d_in[16];
  const float* Whp   = (const float*)d_in[17];
  const float* bhp   = (const float*)d_in[18];
  const float* Wk    = (const float*)d_in[19];
  const float* bk    = (const float*)d_in[20];

  char* ws = (char*)d_ws;
  unsigned short* xcat   = (unsigned short*)(ws);                 // 16,777,216 B
  unsigned short* Wcat   = (unsigned short*)(ws + 16777216);      //  2,621,440 B
  unsigned short* Whb    = (unsigned short*)(ws + 19398656);      //  2,621,440 B
  unsigned short* Wlb    = (unsigned short*)(ws + 22020096);      //  2,621,440 B
  unsigned short* Whpb   = (unsigned short*)(ws + 24641536);      //  2,621,440 B
  unsigned short* Wkb    = (unsigned short*)(ws + 27262976);      //  2,621,440 B
  unsigned short* hprevb = (unsigned short*)(ws + 29884416);      // 16,777,216 B
  unsigned short* kb16   = (unsigned short*)(ws + 46661632);      // 16,777,216 B
  float* bias0           = (float*)(ws + 63438848);               //     10,240 B
  float* bias1           = (float*)(ws + 63449088);
  float* bias2           = (float*)(ws + 63459328);
  float* biasD           = (float*)(ws + 63469568);
  unsigned short* bufA   = (unsigned short*)(ws + 63479808);      // 83,886,080 B
  unsigned short* bufB   = (unsigned short*)(ws + 147365888);     // 83,886,080 B
  // total: 231,251,968 B

  pack_x<<<32768, 256, 0, stream>>>(word, tag, rel, xcat);
  pack_w<<<5120, 256, 0, stream>>>(Ww, Wt, Wr, Wcat);
  cvt_bf16<<<1280, 256, 0, stream>>>(Wh, Whb, 1310720);
  cvt_bf16<<<1280, 256, 0, stream>>>(Wl, Wlb, 1310720);
  cvt_bf16<<<1280, 256, 0, stream>>>(Whp, Whpb, 1310720);
  cvt_bf16<<<1280, 256, 0, stream>>>(Wk, Wkb, 1310720);
  cvt_bf16<<<8192, 256, 0, stream>>>(hprev, hprevb, 8388608);
  cvt_bf16<<<8192, 256, 0, stream>>>(kin, kb16, 8388608);
  pack_bias<<<10, 256, 0, stream>>>(bw, bt, br, bh, bl, bhp, bk, bias0, bias1, bias2, biasD);

  dim3 grid(NROWS / 128, HDIM / 128, GATES);
  // h0 = tanh(xcat W0^T + b0)
  gemm_nt<0><<<grid, 256, 0, stream>>>(xcat, nullptr, Wcat, nullptr, bias0, nullptr, bufA, 0, 16);
  // h1 = tanh(h0 Whid^T + bhid)
  gemm_nt<0><<<grid, 256, 0, stream>>>(bufA, nullptr, Whb, nullptr, bias1, nullptr, bufB, 1, 16);
  // m = tanh(h1 Wlast^T + blast)
  gemm_nt<0><<<grid, 256, 0, stream>>>(bufB, nullptr, Wlb, nullptr, bias2, nullptr, bufA, 1, 16);
  // gates = act(hprev Whp^T + k Wk^T + bhp + bk + m)
  gemm_nt<1><<<grid, 256, 0, stream>>>(hprevb, kb16, Whpb, Wkb, biasD, bufA, bufB, 0, 32);
  // c = i*u + f_down*q + f_left*c_prev ; h = o*tanh(c)
  combine<<<4096, 256, 0, stream>>>(bufB, qin, cprev, (float*)d_out);
}

// Round 7
// 510.419 us; speedup vs baseline: 1.7839x; 1.0789x over previous
//
#include <hip/hip_runtime.h>
#include <math.h>

#define NROWS 16384
#define GATES 5
#define HDIM 512

using bf16x8 = __attribute__((ext_vector_type(8))) short;
using f32x4  = __attribute__((ext_vector_type(4))) float;

__device__ inline float b2f(unsigned short s) {
  unsigned int u = ((unsigned int)s) << 16;
  return __builtin_bit_cast(float, u);
}
__device__ inline unsigned short f2b(float f) {
  unsigned int u = __builtin_bit_cast(unsigned int, f);
  u += 0x7fffu + ((u >> 16) & 1u);   // RNE
  return (unsigned short)(u >> 16);
}

// fast activations: v_exp_f32 (2^x) + v_rcp_f32, ~5 inst, saturate correctly
__device__ inline float fast_sigmoid(float x) {
  float t = __builtin_amdgcn_exp2f(-1.4426950408889634f * x);
  return __builtin_amdgcn_rcpf(1.0f + t);
}
__device__ inline float fast_tanh(float x) {
  float t = __builtin_amdgcn_exp2f(2.8853900817779268f * x);
  return 1.0f - 2.0f * __builtin_amdgcn_rcpf(1.0f + t);
}

__device__ inline void gload_lds16(const unsigned short* g, unsigned short* l) {
  __builtin_amdgcn_global_load_lds(
      (const __attribute__((address_space(1))) unsigned int*)(g),
      (__attribute__((address_space(3))) unsigned int*)(l), 16, 0, 0);
}

// ---------------- packing / conversion kernels (f32 -> bf16) ----------------

__global__ void pack_x(const float* __restrict__ word,
                       const float* __restrict__ tag,
                       const float* __restrict__ rel,
                       unsigned short* __restrict__ xcat) {
  int idx = blockIdx.x * 256 + threadIdx.x;       // N*512
  int n = idx >> 9, c = idx & 511;
  float v = 0.f;
  if (c < 300)      v = word[n * 300 + c];
  else if (c < 350) v = tag[n * 50 + (c - 300)];
  else if (c < 400) v = rel[n * 50 + (c - 350)];
  xcat[idx] = f2b(v);
}

__global__ void pack_w(const float* __restrict__ Ww,
                       const float* __restrict__ Wt,
                       const float* __restrict__ Wr,
                       unsigned short* __restrict__ Wcat) {
  int idx = blockIdx.x * 256 + threadIdx.x;       // G*512*512
  int gh = idx >> 9;                              // g*512 + h
  int c = idx & 511;
  float v = 0.f;
  if (c < 300)      v = Ww[gh * 300 + c];
  else if (c < 350) v = Wt[gh * 50 + (c - 300)];
  else if (c < 400) v = Wr[gh * 50 + (c - 350)];
  Wcat[idx] = f2b(v);
}

__global__ void cvt_bf16(const float* __restrict__ in,
                         unsigned short* __restrict__ out, int n) {
  int i = (blockIdx.x * 256 + threadIdx.x) * 4;
  if (i >= n) return;
  float4 v = *(const float4*)(in + i);
  ushort4 o;
  o.x = f2b(v.x); o.y = f2b(v.y); o.z = f2b(v.z); o.w = f2b(v.w);
  *(ushort4*)(out + i) = o;
}

__global__ void pack_bias(const float* __restrict__ bw, const float* __restrict__ bt,
                          const float* __restrict__ br, const float* __restrict__ bh,
                          const float* __restrict__ bl, const float* __restrict__ bhp,
                          const float* __restrict__ bk,
                          float* bias0, float* bias1, float* bias2, float* biasD) {
  int i = blockIdx.x * 256 + threadIdx.x;         // G*512
  if (i < GATES * HDIM) {
    bias0[i] = bw[i] + bt[i] + br[i];
    bias1[i] = bh[i];
    bias2[i] = bl[i];
    biasD[i] = bhp[i] + bk[i];
  }
}

// ---------------- GEMM: 128x256 tile, BK=32, 4 waves, 3-buf counted-vmcnt ----
// Wave = 64 rows x 128 cols -> 32 MFMA per chunk per wave (2.7x density vs 128^2).
// Swizzle: LDS[r][ssl] holds global slot (ssl ^ ((r>>1)&3)) -> 2-way-min bank
// spread on b128 reads (read slot = q ^ ((fr>>1)&3), row-invariant per lane).
// Pipeline: 3 LDS bufs, 2 chunks prefetched, steady s_waitcnt vmcnt(6).
// MODE 0: Out = tanh(A*W[g]^T + bias[g]); MODE 1: + A2*W2[g]^T + Madd, gate act.

template<int MODE>
__global__ __launch_bounds__(256, 2) void gemm_nt(
    const unsigned short* __restrict__ A1, const unsigned short* __restrict__ A2,
    const unsigned short* __restrict__ W1, const unsigned short* __restrict__ W2,
    const float* __restrict__ bias,
    const unsigned short* __restrict__ Madd,
    unsigned short* __restrict__ Out,
    int aPerGate, int S)       // S = K/32 chunks (16 or 32)
{
  __shared__ __align__(16) unsigned short Alds[3][128 * 32];   // 24 KB
  __shared__ __align__(16) unsigned short Blds[3][256 * 32];   // 48 KB

  const int t = threadIdx.x;
  const int row0 = blockIdx.x * 128;   // N tile
  const int col0 = blockIdx.y * 256;   // H tile
  const int g = blockIdx.z;

  const size_t wslab = (size_t)g * HDIM * HDIM;
  const size_t aslab = aPerGate ? (size_t)g * NROWS * HDIM : 0;

  f32x4 acc[4][8];
#pragma unroll
  for (int mi = 0; mi < 4; ++mi)
#pragma unroll
    for (int ni = 0; ni < 8; ++ni)
      acc[mi][ni] = (f32x4){0.f, 0.f, 0.f, 0.f};

  const int w = t >> 6, l = t & 63;
  const int wrow = (w >> 1) * 64, wcol = (w & 1) * 128;
  const int fr = l & 15, q = l >> 4;
  const int slot = (q ^ ((fr >> 1) & 3)) * 8;    // read k-slot (elements), row-invariant

  // staging: dst byte = j*4096 + t*16 (lane-linear, m104); source slot inverse-swizzled
  const int rA  = t >> 2;        // row base 0..63
  const int ssl = t & 3;         // 16B slot
  auto stage = [&](int c, int buf) {
    const unsigned short* Ab; const unsigned short* Wb; int kloc;
    if (MODE == 1 && c >= 16) { Ab = A2;         Wb = W2 + wslab; kloc = (c - 16) * 32; }
    else                      { Ab = A1 + aslab; Wb = W1 + wslab; kloc = c * 32; }
#pragma unroll
    for (int j = 0; j < 2; ++j) {
      const int r  = j * 64 + rA;
      const int sg = (ssl ^ ((r >> 1) & 3)) * 8;
      gload_lds16(Ab + (size_t)(row0 + r) * HDIM + kloc + sg, &Alds[buf][r * 32 + ssl * 8]);
    }
#pragma unroll
    for (int j = 0; j < 4; ++j) {
      const int r  = j * 64 + rA;
      const int sg = (ssl ^ ((r >> 1) & 3)) * 8;
      gload_lds16(Wb + (size_t)(col0 + r) * HDIM + kloc + sg, &Blds[buf][r * 32 + ssl * 8]);
    }
  };

  stage(0, 0); stage(1, 1);      // 12 loads/thread in flight

  for (int s = 0; s < S; ++s) {
    // chunk s must land; keep chunk s+1 (6 loads) in flight
    if (s < S - 1) asm volatile("s_waitcnt vmcnt(6)" ::: "memory");
    else           asm volatile("s_waitcnt vmcnt(0)" ::: "memory");
    __builtin_amdgcn_s_barrier();

    if (s + 2 < S) stage(s + 2, (s + 2) % 3);

    const int buf = s % 3;
    bf16x8 af[4], bfv[8];
#pragma unroll
    for (int mi = 0; mi < 4; ++mi)
      af[mi] = *reinterpret_cast<const bf16x8*>(&Alds[buf][(wrow + mi * 16 + fr) * 32 + slot]);
#pragma unroll
    for (int ni = 0; ni < 8; ++ni)
      bfv[ni] = *reinterpret_cast<const bf16x8*>(&Blds[buf][(wcol + ni * 16 + fr) * 32 + slot]);
    __builtin_amdgcn_s_setprio(1);
#pragma unroll
    for (int mi = 0; mi < 4; ++mi)
#pragma unroll
      for (int ni = 0; ni < 8; ++ni)
        acc[mi][ni] = __builtin_amdgcn_mfma_f32_16x16x32_bf16(af[mi], bfv[ni], acc[mi][ni], 0, 0, 0);
    __builtin_amdgcn_s_setprio(0);
  }

  // epilogue: C/D layout col=lane&15, row=(lane>>4)*4+j   [m89/m91]
  const int crow = (l >> 4) * 4, ccol = l & 15;
  unsigned short* outg = Out + (size_t)g * NROWS * HDIM;
#pragma unroll
  for (int mi = 0; mi < 4; ++mi) {
#pragma unroll
    for (int ni = 0; ni < 8; ++ni) {
      const int hcol = col0 + wcol + ni * 16 + ccol;
      const float bb = bias[g * HDIM + hcol];
#pragma unroll
      for (int j = 0; j < 4; ++j) {
        const int nrow = row0 + wrow + mi * 16 + crow + j;
        float v = acc[mi][ni][j] + bb;
        if (MODE == 1) {
          v += b2f(Madd[(size_t)g * NROWS * HDIM + (size_t)nrow * HDIM + hcol]);
          v = (g < 4) ? fast_sigmoid(v) : fast_tanh(v);
        } else {
          v = fast_tanh(v);
        }
        outg[(size_t)nrow * HDIM + hcol] = f2b(v);
      }
    }
  }
}

// ---------------- final elementwise combine (f32 q/c_prev, f32 out) ----------------

__device__ inline float exb(const uint4& v, int j) {
  unsigned int wd = ((const unsigned int*)&v)[j >> 1];
  return b2f((unsigned short)(wd >> ((j & 1) * 16)));
}

__global__ void combine(const unsigned short* __restrict__ gates,
                        const float* __restrict__ q,
                        const float* __restrict__ cp,
                        float* __restrict__ out) {
  const size_t NM = (size_t)NROWS * HDIM;
  size_t i8 = ((size_t)blockIdx.x * 256 + threadIdx.x) * 8;
  if (i8 >= NM) return;
  uint4 gi = *(const uint4*)(gates + 0 * NM + i8);
  uint4 gf = *(const uint4*)(gates + 1 * NM + i8);
  uint4 gl = *(const uint4*)(gates + 2 * NM + i8);
  uint4 go = *(const uint4*)(gates + 3 * NM + i8);
  uint4 gu = *(const uint4*)(gates + 4 * NM + i8);
  float4 q0 = *(const float4*)(q + i8);
  float4 q1 = *(const float4*)(q + i8 + 4);
  float4 p0 = *(const float4*)(cp + i8);
  float4 p1 = *(const float4*)(cp + i8 + 4);
  float qv[8] = {q0.x, q0.y, q0.z, q0.w, q1.x, q1.y, q1.z, q1.w};
  float pv[8] = {p0.x, p0.y, p0.z, p0.w, p1.x, p1.y, p1.z, p1.w};
  float hv[8], cv[8];
#pragma unroll
  for (int j = 0; j < 8; ++j) {
    float c = exb(gi, j) * exb(gu, j) + exb(gf, j) * qv[j] + exb(gl, j) * pv[j];
    hv[j] = exb(go, j) * fast_tanh(c);
    cv[j] = c;
  }
  *(float4*)(out + i8)      = make_float4(hv[0], hv[1], hv[2], hv[3]);
  *(float4*)(out + i8 + 4)  = make_float4(hv[4], hv[5], hv[6], hv[7]);
  *(float4*)(out + NM + i8)     = make_float4(cv[0], cv[1], cv[2], cv[3]);
  *(float4*)(out + NM + i8 + 4) = make_float4(cv[4], cv[5], cv[6], cv[7]);
}

// ---------------- launch ----------------

extern "C" void kernel_launch(void* const* d_in, const int* in_sizes, int n_in,
                              void* d_out, int out_size, void* d_ws, size_t ws_size,
                              hipStream_t stream) {
  const float* word  = (const float*)d_in[0];
  const float* tag   = (const float*)d_in[1];
  const float* rel   = (const float*)d_in[2];
  const float* kin   = (const float*)d_in[3];
  const float* qin   = (const float*)d_in[4];
  const float* hprev = (const float*)d_in[5];
  const float* cprev = (const float*)d_in[6];
  const float* Ww    = (const float*)d_in[7];
  const float* bw    = (const float*)d_in[8];
  const float* Wt    = (const float*)d_in[9];
  const float* bt    = (const float*)d_in[10];
  const float* Wr    = (const float*)d_in[11];
  const float* br    = (const float*)d_in[12];
  const float* Wh    = (const float*)d_in[13];
  const float* bh    = (const float*)d_in[14];
  const float* Wl    = (const float*)d_in[15];
  const float* bl    = (const float*)d_in[16];
  const float* Whp   = (const float*)d_in[17];
  const float* bhp   = (const float*)d_in[18];
  const float* Wk    = (const float*)d_in[19];
  const float* bk    = (const float*)d_in[20];

  char* ws = (char*)d_ws;
  unsigned short* xcat   = (unsigned short*)(ws);                 // 16,777,216 B
  unsigned short* Wcat   = (unsigned short*)(ws + 16777216);      //  2,621,440 B
  unsigned short* Whb    = (unsigned short*)(ws + 19398656);      //  2,621,440 B
  unsigned short* Wlb    = (unsigned short*)(ws + 22020096);      //  2,621,440 B
  unsigned short* Whpb   = (unsigned short*)(ws + 24641536);      //  2,621,440 B
  unsigned short* Wkb    = (unsigned short*)(ws + 27262976);      //  2,621,440 B
  unsigned short* hprevb = (unsigned short*)(ws + 29884416);      // 16,777,216 B
  unsigned short* kb16   = (unsigned short*)(ws + 46661632);      // 16,777,216 B
  float* bias0           = (float*)(ws + 63438848);               //     10,240 B
  float* bias1           = (float*)(ws + 63449088);
  float* bias2           = (float*)(ws + 63459328);
  float* biasD           = (float*)(ws + 63469568);
  unsigned short* bufA   = (unsigned short*)(ws + 63479808);      // 83,886,080 B
  unsigned short* bufB   = (unsigned short*)(ws + 147365888);     // 83,886,080 B
  // total: 231,251,968 B

  pack_x<<<32768, 256, 0, stream>>>(word, tag, rel, xcat);
  pack_w<<<5120, 256, 0, stream>>>(Ww, Wt, Wr, Wcat);
  cvt_bf16<<<1280, 256, 0, stream>>>(Wh, Whb, 1310720);
  cvt_bf16<<<1280, 256, 0, stream>>>(Wl, Wlb, 1310720);
  cvt_bf16<<<1280, 256, 0, stream>>>(Whp, Whpb, 1310720);
  cvt_bf16<<<1280, 256, 0, stream>>>(Wk, Wkb, 1310720);
  cvt_bf16<<<8192, 256, 0, stream>>>(hprev, hprevb, 8388608);
  cvt_bf16<<<8192, 256, 0, stream>>>(kin, kb16, 8388608);
  pack_bias<<<10, 256, 0, stream>>>(bw, bt, br, bh, bl, bhp, bk, bias0, bias1, bias2, biasD);

  dim3 grid(NROWS / 128, HDIM / 256, GATES);
  // h0 = tanh(xcat W0^T + b0)
  gemm_nt<0><<<grid, 256, 0, stream>>>(xcat, nullptr, Wcat, nullptr, bias0, nullptr, bufA, 0, 16);
  // h1 = tanh(h0 Whid^T + bhid)
  gemm_nt<0><<<grid, 256, 0, stream>>>(bufA, nullptr, Whb, nullptr, bias1, nullptr, bufB, 1, 16);
  // m = tanh(h1 Wlast^T + blast)
  gemm_nt<0><<<grid, 256, 0, stream>>>(bufB, nullptr, Wlb, nullptr, bias2, nullptr, bufA, 1, 16);
  // gates = act(hprev Whp^T + k Wk^T + bhp + bk + m)
  gemm_nt<1><<<grid, 256, 0, stream>>>(hprevb, kb16, Whpb, Wkb, biasD, bufA, bufB, 0, 32);
  // c = i*u + f_down*q + f_left*c_prev ; h = o*tanh(c)
  combine<<<4096, 256, 0, stream>>>(bufB, qin, cprev, (float*)d_out);
}